// Round 2
// baseline (54.038 us; speedup 1.0000x reference)
//
#include <hip/hip_runtime.h>

// SoftDiceLoss: predictions [B=8, C=16, H=512, W=512] fp32, targets [B,H,W] int32.
// out[b] = -(1/C) * sum_c (2*overlap[b,c] + 1) / (i_sum[b,c] + count[b,c] + 1)
//
// Stage 1: 2048 blocks = (8 batches x 2 channel-groups x 128 chunks) x 256 thr.
//   Each block covers 2048 spatial positions x 8 channels. Per-class count is
//   kept as packed 4-bit nibbles in one 64-bit reg (max 8 adds/nibble, no
//   carry-out; out-of-group classes land in the discarded high word).
//   Wave shuffle + LDS reduce -> partial[block][24] in d_ws (deterministic).
// Stage 2: 8 blocks (one per batch): waves 0-1 reduce channel-group 0 rows,
//   waves 2-3 group 1; then 16 threads form frac and reduce to out[b].

constexpr int  C_CLS   = 16;
constexpr int  CPB     = 8;            // channels per block
constexpr long HW      = 512L * 512L;  // 262144
constexpr int  BATCH   = 8;
constexpr int  CHUNKS  = 128;
constexpr int  THREADS = 256;
constexpr int  ITERS   = 2;            // 2 x (256 thr x 4 floats) = 2048 pos/block
constexpr int  NPART   = 3 * CPB;      // 24 floats per partial row

__global__ __launch_bounds__(THREADS, 8)
void dice_partial_kernel(const float* __restrict__ pred,
                         const int*   __restrict__ tgt,
                         float*       __restrict__ partial) {
    const int g     = blockIdx.x;
    const int chunk = g & (CHUNKS - 1);
    const int cg    = (g >> 7) & 1;
    const int b     = g >> 8;
    const int cbase = cg * CPB;
    const int tid   = threadIdx.x;

    float isum[CPB], ov[CPB];
#pragma unroll
    for (int c = 0; c < CPB; ++c) { isum[c] = 0.f; ov[c] = 0.f; }
    unsigned long long cnt = 0ull;

    const float* pb = pred + ((long)b * C_CLS + cbase) * HW;
    const int*   tb = tgt  + (long)b * HW;

#pragma unroll
    for (int it = 0; it < ITERS; ++it) {
        const long pos = (long)chunk * 2048 + it * 1024 + tid * 4;
        const int4 t = *reinterpret_cast<const int4*>(tb + pos);
        cnt += 1ull << ((4u * (unsigned)(t.x - cbase)) & 63u);
        cnt += 1ull << ((4u * (unsigned)(t.y - cbase)) & 63u);
        cnt += 1ull << ((4u * (unsigned)(t.z - cbase)) & 63u);
        cnt += 1ull << ((4u * (unsigned)(t.w - cbase)) & 63u);
#pragma unroll
        for (int c = 0; c < CPB; ++c) {
            const float4 p = *reinterpret_cast<const float4*>(pb + (long)c * HW + pos);
            isum[c] += (p.x + p.y) + (p.z + p.w);
            const int cc = cbase + c;
            ov[c] += ((t.x == cc) ? p.x : 0.f) + ((t.y == cc) ? p.y : 0.f)
                   + ((t.z == cc) ? p.z : 0.f) + ((t.w == cc) ? p.w : 0.f);
        }
    }

    // unpack packed counts (low 32 bits = this block's 8 classes)
    const unsigned clo = (unsigned)cnt;
    float cntf[CPB];
#pragma unroll
    for (int c = 0; c < CPB; ++c)
        cntf[c] = (float)((clo >> (4 * c)) & 0xFu);

    // wave64 tree reduce the 24 accumulators
    const int lane = tid & 63;
    const int wv   = tid >> 6;
#pragma unroll
    for (int c = 0; c < CPB; ++c) {
#pragma unroll
        for (int off = 32; off > 0; off >>= 1) {
            isum[c] += __shfl_down(isum[c], off);
            ov[c]   += __shfl_down(ov[c],   off);
            cntf[c] += __shfl_down(cntf[c], off);
        }
    }

    __shared__ float sm[4][NPART];
    if (lane == 0) {
#pragma unroll
        for (int c = 0; c < CPB; ++c) {
            sm[wv][c * 3 + 0] = isum[c];
            sm[wv][c * 3 + 1] = ov[c];
            sm[wv][c * 3 + 2] = cntf[c];
        }
    }
    __syncthreads();
    if (tid < NPART) {
        partial[(long)g * NPART + tid] =
            (sm[0][tid] + sm[1][tid]) + (sm[2][tid] + sm[3][tid]);
    }
}

__global__ __launch_bounds__(THREADS)
void dice_final_kernel(const float* __restrict__ partial,
                       float*       __restrict__ out) {
    const int b    = blockIdx.x;
    const int tid  = threadIdx.x;     // 0..255: cg = tid>>7, chunk = tid&127
    const int lane = tid & 63;
    const int wv   = tid >> 6;        // waves 0-1: cg0 rows, waves 2-3: cg1 rows

    const int cg    = tid >> 7;
    const int chunk = tid & (CHUNKS - 1);
    const long row  = ((long)(b * 2 + cg) * CHUNKS + chunk) * NPART;

    float acc[NPART];
#pragma unroll
    for (int k = 0; k < NPART; ++k) acc[k] = partial[row + k];

#pragma unroll
    for (int k = 0; k < NPART; ++k) {
#pragma unroll
        for (int off = 32; off > 0; off >>= 1)
            acc[k] += __shfl_down(acc[k], off);
    }

    __shared__ float sm[4][NPART];
    if (lane == 0) {
#pragma unroll
        for (int k = 0; k < NPART; ++k) sm[wv][k] = acc[k];
    }
    __syncthreads();

    if (tid < C_CLS) {
        const int gcg = tid >> 3;      // which channel group this class lives in
        const int cc  = tid & 7;
        const float is = sm[2 * gcg][cc * 3 + 0] + sm[2 * gcg + 1][cc * 3 + 0];
        const float o  = sm[2 * gcg][cc * 3 + 1] + sm[2 * gcg + 1][cc * 3 + 1];
        const float cn = sm[2 * gcg][cc * 3 + 2] + sm[2 * gcg + 1][cc * 3 + 2];
        float frac = (2.f * o + 1.f) / (is + cn + 1.f);
#pragma unroll
        for (int off = 8; off > 0; off >>= 1)
            frac += __shfl_down(frac, off, 16);
        if (tid == 0) out[b] = -frac * (1.f / (float)C_CLS);
    }
}

extern "C" void kernel_launch(void* const* d_in, const int* in_sizes, int n_in,
                              void* d_out, int out_size, void* d_ws, size_t ws_size,
                              hipStream_t stream) {
    const float* pred = (const float*)d_in[0];
    const int*   tgt  = (const int*)d_in[1];
    float*       out  = (float*)d_out;
    float*       partial = (float*)d_ws;   // 2048 * 24 * 4 B = 196608 B

    dice_partial_kernel<<<BATCH * 2 * CHUNKS, THREADS, 0, stream>>>(pred, tgt, partial);
    dice_final_kernel<<<BATCH, THREADS, 0, stream>>>(partial, out);
}

// Round 3
// 44.595 us; speedup vs baseline: 1.2117x; 1.2117x over previous
//
#include <hip/hip_runtime.h>

// SoftDiceLoss: predictions [B=8, C=16, H=512, W=512] fp32, targets [B,H,W] int32.
// out[b] = -(1/C) * sum_c (2*overlap[b,c] + 1) / (i_sum[b,c] + count[b,c] + 1)
//
// Stage 1: 2048 blocks = (8 batches x 256 chunks) x 256 threads.
//   Each THREAD handles exactly 4 spatial positions (one int4 + 16 float4
//   loads, all in flight simultaneously ~ 17 KB/wave of MLP). Class counts
//   are packed as 16 x 4-bit nibbles in ONE u64 (max 4 adds per nibble).
//   Latency hiding comes from block turnover (8 blocks/CU cycling through
//   4-waves/SIMD residency), not intra-wave loops.
// Stage 2: 8 blocks (one per batch) x 256 threads, one partial row each.

constexpr int  C_CLS   = 16;
constexpr long HW      = 512L * 512L;  // 262144
constexpr int  BATCH   = 8;
constexpr int  CHUNKS  = 256;          // chunks per batch; 256*1024 = HW
constexpr int  THREADS = 256;
constexpr int  NPART   = 3 * C_CLS;    // 48 floats per partial row

__global__ __launch_bounds__(THREADS, 4)
void dice_partial_kernel(const float* __restrict__ pred,
                         const int*   __restrict__ tgt,
                         float*       __restrict__ partial) {
    const int g     = blockIdx.x;
    const int chunk = g & (CHUNKS - 1);
    const int b     = g >> 8;
    const int tid   = threadIdx.x;

    const long pos = (long)chunk * 1024 + tid * 4;
    const float* pb = pred + (long)b * C_CLS * HW + pos;
    const int4 t = *reinterpret_cast<const int4*>(tgt + (long)b * HW + pos);

    // packed per-class counts: nibble c = #positions with target==c (max 4)
    unsigned long long cnt = 0ull;
    cnt += 1ull << (4u * (unsigned)t.x);
    cnt += 1ull << (4u * (unsigned)t.y);
    cnt += 1ull << (4u * (unsigned)t.z);
    cnt += 1ull << (4u * (unsigned)t.w);

    float isum[C_CLS], ov[C_CLS];
#pragma unroll
    for (int c = 0; c < C_CLS; ++c) {
        const float4 p = *reinterpret_cast<const float4*>(pb + (long)c * HW);
        isum[c] = (p.x + p.y) + (p.z + p.w);
        ov[c]   = ((t.x == c) ? p.x : 0.f) + ((t.y == c) ? p.y : 0.f)
                + ((t.z == c) ? p.z : 0.f) + ((t.w == c) ? p.w : 0.f);
    }

    // unpack counts to floats for the reduction
    float cntf[C_CLS];
#pragma unroll
    for (int c = 0; c < C_CLS; ++c)
        cntf[c] = (float)((unsigned)(cnt >> (4 * c)) & 0xFu);

    // wave64 tree reduce the 48 accumulators
    const int lane = tid & 63;
    const int wv   = tid >> 6;
#pragma unroll
    for (int c = 0; c < C_CLS; ++c) {
#pragma unroll
        for (int off = 32; off > 0; off >>= 1) {
            isum[c] += __shfl_down(isum[c], off);
            ov[c]   += __shfl_down(ov[c],   off);
            cntf[c] += __shfl_down(cntf[c], off);
        }
    }

    __shared__ float sm[4][NPART];
    if (lane == 0) {
#pragma unroll
        for (int c = 0; c < C_CLS; ++c) {
            sm[wv][c * 3 + 0] = isum[c];
            sm[wv][c * 3 + 1] = ov[c];
            sm[wv][c * 3 + 2] = cntf[c];
        }
    }
    __syncthreads();
    if (tid < NPART) {
        partial[(long)g * NPART + tid] =
            (sm[0][tid] + sm[1][tid]) + (sm[2][tid] + sm[3][tid]);
    }
}

__global__ __launch_bounds__(THREADS)
void dice_final_kernel(const float* __restrict__ partial,
                       float*       __restrict__ out) {
    const int b    = blockIdx.x;
    const int tid  = threadIdx.x;     // one partial row per thread (256 rows/batch)
    const int lane = tid & 63;
    const int wv   = tid >> 6;

    const float* row = partial + ((long)b * CHUNKS + tid) * NPART;
    float acc[NPART];
#pragma unroll
    for (int k = 0; k < NPART; ++k) acc[k] = row[k];

#pragma unroll
    for (int k = 0; k < NPART; ++k) {
#pragma unroll
        for (int off = 32; off > 0; off >>= 1)
            acc[k] += __shfl_down(acc[k], off);
    }

    __shared__ float sm[4][NPART];
    if (lane == 0) {
#pragma unroll
        for (int k = 0; k < NPART; ++k) sm[wv][k] = acc[k];
    }
    __syncthreads();

    if (tid < C_CLS) {
        const float is = (sm[0][tid * 3 + 0] + sm[1][tid * 3 + 0])
                       + (sm[2][tid * 3 + 0] + sm[3][tid * 3 + 0]);
        const float o  = (sm[0][tid * 3 + 1] + sm[1][tid * 3 + 1])
                       + (sm[2][tid * 3 + 1] + sm[3][tid * 3 + 1]);
        const float cn = (sm[0][tid * 3 + 2] + sm[1][tid * 3 + 2])
                       + (sm[2][tid * 3 + 2] + sm[3][tid * 3 + 2]);
        float frac = (2.f * o + 1.f) / (is + cn + 1.f);
#pragma unroll
        for (int off = 8; off > 0; off >>= 1)
            frac += __shfl_down(frac, off, 16);
        if (tid == 0) out[b] = -frac * (1.f / (float)C_CLS);
    }
}

extern "C" void kernel_launch(void* const* d_in, const int* in_sizes, int n_in,
                              void* d_out, int out_size, void* d_ws, size_t ws_size,
                              hipStream_t stream) {
    const float* pred = (const float*)d_in[0];
    const int*   tgt  = (const int*)d_in[1];
    float*       out  = (float*)d_out;
    float*       partial = (float*)d_ws;   // 2048 * 48 * 4 B = 393216 B

    dice_partial_kernel<<<BATCH * CHUNKS, THREADS, 0, stream>>>(pred, tgt, partial);
    dice_final_kernel<<<BATCH, THREADS, 0, stream>>>(partial, out);
}

// Round 4
// 35.945 us; speedup vs baseline: 1.5034x; 1.2407x over previous
//
#include <hip/hip_runtime.h>

// SoftDiceLoss: predictions [B=8, C=16, H=512, W=512] fp32, targets [B,H,W] int32.
// out[b] = -(1/C) * sum_c (2*overlap[b,c] + 1) / (i_sum[b,c] + count[b,c] + 1)
//
// Stage 0: targets -> one-hot BITPLANES in d_ws: bitp[b][c][HW/32] (4 MB).
//   Wave covers 64 consecutive positions; __ballot(t==c) = 2 mask words.
// Stage 1: 2048 blocks; each block = one contiguous 64 KB slab of ONE
//   (b,c) plane. Pure sequential float4 streaming + 1 broadcast u32 mask
//   word per 8 lanes. Per-thread state: isum, ov, popcount (3 regs).
// Stage 2: 8 blocks (one per batch): thread (c,chunk) sums partial triples,
//   width-16 shuffle reduce over chunks, LDS reduce over classes.

constexpr int  C_CLS   = 16;
constexpr long HW      = 512L * 512L;   // 262144 positions per (b,c) plane
constexpr int  BATCH   = 8;
constexpr int  WPP     = (int)(HW / 32);       // 8192 mask words per plane
constexpr int  CHUNKS  = 16;                   // chunks per plane
constexpr int  CHUNK_F = (int)(HW / CHUNKS);   // 16384 floats per chunk
constexpr int  ITERS   = CHUNK_F / (256 * 4);  // 16 float4-iters per thread

__global__ __launch_bounds__(256)
void build_masks_kernel(const int* __restrict__ tgt,
                        unsigned*  __restrict__ bitp) {
    const long i    = (long)blockIdx.x * 256 + threadIdx.x;  // global position
    const int  lane = threadIdx.x & 63;
    const int  t    = tgt[i];

    unsigned long long mym = 0ull;
#pragma unroll
    for (int c = 0; c < C_CLS; ++c) {
        const unsigned long long m = __ballot(t == c);
        if (lane == c) mym = m;
    }
    if (lane < C_CLS) {
        const long wavebase = i - lane;          // multiple of 64, same batch
        const int  b        = (int)(wavebase / HW);
        const int  widx     = (int)((wavebase % HW) >> 5);   // even
        unsigned long long* dst = reinterpret_cast<unsigned long long*>(
            bitp + ((long)b * C_CLS + lane) * WPP + widx);
        *dst = mym;
    }
}

__global__ __launch_bounds__(256, 4)
void dice_partial_kernel(const float*    __restrict__ pred,
                         const unsigned* __restrict__ bitp,
                         float*          __restrict__ partial) {
    const int g     = blockIdx.x;
    const int chunk = g & (CHUNKS - 1);
    const int plane = g >> 4;                    // b*16 + c
    const int tid   = threadIdx.x;

    const float*    p0 = pred + (long)plane * HW + (long)chunk * CHUNK_F;
    const unsigned* mw = bitp + (long)plane * WPP + chunk * (CHUNK_F / 32);

    float isum = 0.f, ov = 0.f;
    int   cnt  = 0;
#pragma unroll 8
    for (int it = 0; it < ITERS; ++it) {
        const float4 p = *reinterpret_cast<const float4*>(p0 + it * 1024 + tid * 4);
        const unsigned bits = (mw[it * 32 + (tid >> 3)] >> ((tid & 7) * 4)) & 0xFu;
        isum += (p.x + p.y) + (p.z + p.w);
        ov   += ((bits & 1u) ? p.x : 0.f) + ((bits & 2u) ? p.y : 0.f)
              + ((bits & 4u) ? p.z : 0.f) + ((bits & 8u) ? p.w : 0.f);
        cnt  += __popc(bits);
    }
    float cntf = (float)cnt;

    const int lane = tid & 63;
    const int wv   = tid >> 6;
#pragma unroll
    for (int off = 32; off > 0; off >>= 1) {
        isum += __shfl_down(isum, off);
        ov   += __shfl_down(ov,   off);
        cntf += __shfl_down(cntf, off);
    }

    __shared__ float sm[4][3];
    if (lane == 0) {
        sm[wv][0] = isum; sm[wv][1] = ov; sm[wv][2] = cntf;
    }
    __syncthreads();
    if (tid < 3) {
        partial[(long)g * 3 + tid] =
            (sm[0][tid] + sm[1][tid]) + (sm[2][tid] + sm[3][tid]);
    }
}

__global__ __launch_bounds__(256)
void dice_final_kernel(const float* __restrict__ partial,
                       float*       __restrict__ out) {
    const int b     = blockIdx.x;
    const int tid   = threadIdx.x;    // c = tid>>4, chunk = tid&15
    const int c     = tid >> 4;
    const int chunk = tid & 15;

    const float* r = partial + ((long)b * 256 + tid) * 3;
    float is = r[0], ov = r[1], cn = r[2];
#pragma unroll
    for (int off = 8; off > 0; off >>= 1) {
        is += __shfl_down(is, off, 16);
        ov += __shfl_down(ov, off, 16);
        cn += __shfl_down(cn, off, 16);
    }

    __shared__ float sfrac[C_CLS];
    if (chunk == 0)
        sfrac[c] = (2.f * ov + 1.f) / (is + cn + 1.f);
    __syncthreads();

    if (tid == 0) {
        float s = 0.f;
#pragma unroll
        for (int k = 0; k < C_CLS; ++k) s += sfrac[k];
        out[b] = -s * (1.f / (float)C_CLS);
    }
}

extern "C" void kernel_launch(void* const* d_in, const int* in_sizes, int n_in,
                              void* d_out, int out_size, void* d_ws, size_t ws_size,
                              hipStream_t stream) {
    const float* pred = (const float*)d_in[0];
    const int*   tgt  = (const int*)d_in[1];
    float*       out  = (float*)d_out;

    unsigned* bitp    = (unsigned*)d_ws;                       // 4 MiB
    float*    partial = (float*)((char*)d_ws + (size_t)BATCH * C_CLS * WPP * 4);
                                                               // + 24 KiB

    build_masks_kernel<<<(int)((long)BATCH * HW / 256), 256, 0, stream>>>(tgt, bitp);
    dice_partial_kernel<<<BATCH * C_CLS * CHUNKS, 256, 0, stream>>>(pred, bitp, partial);
    dice_final_kernel<<<BATCH, 256, 0, stream>>>(partial, out);
}

// Round 5
// 34.780 us; speedup vs baseline: 1.5537x; 1.0335x over previous
//
#include <hip/hip_runtime.h>

// SoftDiceLoss: predictions [B=8, C=16, H=512, W=512] fp32, targets [B,H,W] int32.
// out[b] = -(1/C) * sum_c (2*overlap[b,c] + 1) / (i_sum[b,c] + count[b,c] + 1)
//
// Stage 0: targets -> one-hot BITPLANES in d_ws: bitp[b][c][HW/32] (4 MB).
//   2048 blocks, grid-stride x4; wave covers 64 consecutive positions;
//   __ballot(t==c) = 2 mask words per (wave, class).
// Stage 1: 2048 blocks; each block = one contiguous 64 KB slab of ONE
//   (b,c) plane. Pure sequential float4 streaming + 1 broadcast u32 mask
//   word per 8 lanes. Per-thread state: isum, ov, popcount (3 regs).
//   __launch_bounds__(256,8): <=64 VGPR -> 8 blocks/CU -> ALL 2048 blocks
//   resident in ONE round (no second-round ramp). Unroll 4 keeps regs low;
//   2x waves x 1/2 unroll depth = same in-flight bytes per CU.
// Stage 2: 8 blocks (one per batch): thread (c,chunk) sums partial triples,
//   width-16 shuffle reduce over chunks, LDS reduce over classes.

constexpr int  C_CLS   = 16;
constexpr long HW      = 512L * 512L;   // 262144 positions per (b,c) plane
constexpr int  BATCH   = 8;
constexpr int  WPP     = (int)(HW / 32);       // 8192 mask words per plane
constexpr int  CHUNKS  = 16;                   // chunks per plane
constexpr int  CHUNK_F = (int)(HW / CHUNKS);   // 16384 floats per chunk
constexpr int  ITERS   = CHUNK_F / (256 * 4);  // 16 float4-iters per thread

__global__ __launch_bounds__(256)
void build_masks_kernel(const int* __restrict__ tgt,
                        unsigned*  __restrict__ bitp) {
    const int  lane = threadIdx.x & 63;
    const long i0   = (long)blockIdx.x * 256 + threadIdx.x;
    const long stride = 2048L * 256L;            // total threads
#pragma unroll
    for (int it = 0; it < 4; ++it) {
        const long i = i0 + it * stride;
        const int  t = tgt[i];
        unsigned long long mym = 0ull;
#pragma unroll
        for (int c = 0; c < C_CLS; ++c) {
            const unsigned long long m = __ballot(t == c);
            if (lane == c) mym = m;
        }
        if (lane < C_CLS) {
            const long wavebase = i - lane;       // multiple of 64, same batch
            const int  b        = (int)(wavebase / HW);
            const int  widx     = (int)((wavebase % HW) >> 5);   // even
            *reinterpret_cast<unsigned long long*>(
                bitp + ((long)b * C_CLS + lane) * WPP + widx) = mym;
        }
    }
}

__global__ __launch_bounds__(256, 8)
void dice_partial_kernel(const float*    __restrict__ pred,
                         const unsigned* __restrict__ bitp,
                         float*          __restrict__ partial) {
    const int g     = blockIdx.x;
    const int chunk = g & (CHUNKS - 1);
    const int plane = g >> 4;                    // b*16 + c
    const int tid   = threadIdx.x;

    const float*    p0 = pred + (long)plane * HW + (long)chunk * CHUNK_F;
    const unsigned* mw = bitp + (long)plane * WPP + chunk * (CHUNK_F / 32);

    float isum = 0.f, ov = 0.f;
    int   cnt  = 0;
#pragma unroll 4
    for (int it = 0; it < ITERS; ++it) {
        const float4 p = *reinterpret_cast<const float4*>(p0 + it * 1024 + tid * 4);
        const unsigned bits = (mw[it * 32 + (tid >> 3)] >> ((tid & 7) * 4)) & 0xFu;
        isum += (p.x + p.y) + (p.z + p.w);
        ov   += ((bits & 1u) ? p.x : 0.f) + ((bits & 2u) ? p.y : 0.f)
              + ((bits & 4u) ? p.z : 0.f) + ((bits & 8u) ? p.w : 0.f);
        cnt  += __popc(bits);
    }
    float cntf = (float)cnt;

    const int lane = tid & 63;
    const int wv   = tid >> 6;
#pragma unroll
    for (int off = 32; off > 0; off >>= 1) {
        isum += __shfl_down(isum, off);
        ov   += __shfl_down(ov,   off);
        cntf += __shfl_down(cntf, off);
    }

    __shared__ float sm[4][3];
    if (lane == 0) {
        sm[wv][0] = isum; sm[wv][1] = ov; sm[wv][2] = cntf;
    }
    __syncthreads();
    if (tid < 3) {
        partial[(long)g * 3 + tid] =
            (sm[0][tid] + sm[1][tid]) + (sm[2][tid] + sm[3][tid]);
    }
}

__global__ __launch_bounds__(256)
void dice_final_kernel(const float* __restrict__ partial,
                       float*       __restrict__ out) {
    const int b     = blockIdx.x;
    const int tid   = threadIdx.x;    // c = tid>>4, chunk = tid&15
    const int c     = tid >> 4;
    const int chunk = tid & 15;

    const float* r = partial + ((long)b * 256 + tid) * 3;
    float is = r[0], ov = r[1], cn = r[2];
#pragma unroll
    for (int off = 8; off > 0; off >>= 1) {
        is += __shfl_down(is, off, 16);
        ov += __shfl_down(ov, off, 16);
        cn += __shfl_down(cn, off, 16);
    }

    __shared__ float sfrac[C_CLS];
    if (chunk == 0)
        sfrac[c] = (2.f * ov + 1.f) / (is + cn + 1.f);
    __syncthreads();

    if (tid == 0) {
        float s = 0.f;
#pragma unroll
        for (int k = 0; k < C_CLS; ++k) s += sfrac[k];
        out[b] = -s * (1.f / (float)C_CLS);
    }
}

extern "C" void kernel_launch(void* const* d_in, const int* in_sizes, int n_in,
                              void* d_out, int out_size, void* d_ws, size_t ws_size,
                              hipStream_t stream) {
    const float* pred = (const float*)d_in[0];
    const int*   tgt  = (const int*)d_in[1];
    float*       out  = (float*)d_out;

    unsigned* bitp    = (unsigned*)d_ws;                       // 4 MiB
    float*    partial = (float*)((char*)d_ws + (size_t)BATCH * C_CLS * WPP * 4);
                                                               // + 24 KiB

    build_masks_kernel<<<2048, 256, 0, stream>>>(tgt, bitp);
    dice_partial_kernel<<<BATCH * C_CLS * CHUNKS, 256, 0, stream>>>(pred, bitp, partial);
    dice_final_kernel<<<BATCH, 256, 0, stream>>>(partial, out);
}

// Round 6
// 29.940 us; speedup vs baseline: 1.8049x; 1.1616x over previous
//
#include <hip/hip_runtime.h>

// SoftDiceLoss: predictions [B=8, C=16, H=512, W=512] fp32, targets [B,H,W] int32.
// out[b] = -(1/C) * sum_c (2*overlap[b,c] + 1) / (i_sum[b,c] + count[b,c] + 1)
//
// Stage 1: 512 blocks = (8 batches x 64 slabs of 4096 positions) x 256 thr.
//   Each thread owns 16 positions (4 x float4-group). Targets for those
//   positions are packed 4 bits each into ONE u64 (tpack). The 16 pred
//   class-segments are streamed SEQUENTIALLY (one contiguous 16 KB stream
//   at a time, 4 float4 loads in flight per thread). Per class, the match
//   mask for all 16 positions is 5 VALU ops on tpack (exact nibble==c
//   test); count = popcount. Per-class wave reduce -> LDS -> partial in
//   d_ws, component-major [48][512] for coalesced stage-2 reads.
// Stage 2: 8 blocks x 64 threads: thread t reduces partial row t across
//   the batch's 64 slabs; lane 0 computes the 16 fracs and writes out[b].

constexpr int  C_CLS   = 16;
constexpr long HW      = 512L * 512L;   // 262144 positions per (b,c) plane
constexpr int  BATCH   = 8;
constexpr int  SLAB    = 4096;          // positions per block
constexpr int  SLABS   = (int)(HW / SLAB);   // 64 per batch
constexpr int  NBLK    = BATCH * SLABS;      // 512
constexpr int  NPART   = 3 * C_CLS;          // 48 components

__global__ __launch_bounds__(256, 8)
void dice_partial_kernel(const float* __restrict__ pred,
                         const int*   __restrict__ tgt,
                         float*       __restrict__ partial) {
    const int g    = blockIdx.x;
    const int slab = g & (SLABS - 1);
    const int b    = g >> 6;
    const int tid  = threadIdx.x;
    const int lane = tid & 63;
    const int wv   = tid >> 6;

    const long sbase = (long)slab * SLAB;        // within plane
    const int* tb = tgt + (long)b * HW + sbase;

    // pack this thread's 16 target values into one u64 (4 bits each)
    unsigned long long tpack = 0ull;
#pragma unroll
    for (int j = 0; j < 4; ++j) {
        const int4 tv = *reinterpret_cast<const int4*>(tb + j * 1024 + tid * 4);
        const unsigned nib = (unsigned)tv.x | ((unsigned)tv.y << 4)
                           | ((unsigned)tv.z << 8) | ((unsigned)tv.w << 12);
        tpack |= (unsigned long long)nib << (16 * j);
    }

    const float* pb = pred + (long)b * C_CLS * HW + sbase;

    __shared__ float sm[4][NPART];

#pragma unroll
    for (int c = 0; c < C_CLS; ++c) {
        // exact per-nibble (t==c) mask: bit 4i of m = match at position i
        unsigned long long x = tpack ^ ((unsigned long long)c * 0x1111111111111111ull);
        x |= x >> 2;
        x |= x >> 1;
        const unsigned long long m = ~x & 0x1111111111111111ull;

        float isum = 0.f, ov = 0.f;
#pragma unroll
        for (int j = 0; j < 4; ++j) {
            const float4 p = *reinterpret_cast<const float4*>(
                pb + (long)c * HW + j * 1024 + tid * 4);
            const unsigned mb = (unsigned)(m >> (16 * j));
            isum += (p.x + p.y) + (p.z + p.w);
            ov   += ((mb & 0x0001u) ? p.x : 0.f) + ((mb & 0x0010u) ? p.y : 0.f)
                  + ((mb & 0x0100u) ? p.z : 0.f) + ((mb & 0x1000u) ? p.w : 0.f);
        }
        float cntf = (float)__popcll(m);

#pragma unroll
        for (int off = 32; off > 0; off >>= 1) {
            isum += __shfl_down(isum, off);
            ov   += __shfl_down(ov,   off);
            cntf += __shfl_down(cntf, off);
        }
        if (lane == 0) {
            sm[wv][c * 3 + 0] = isum;
            sm[wv][c * 3 + 1] = ov;
            sm[wv][c * 3 + 2] = cntf;
        }
    }

    __syncthreads();
    if (tid < NPART) {
        // component-major layout: partial[comp][block] for coalesced stage-2
        partial[(long)tid * NBLK + g] =
            (sm[0][tid] + sm[1][tid]) + (sm[2][tid] + sm[3][tid]);
    }
}

__global__ __launch_bounds__(64)
void dice_final_kernel(const float* __restrict__ partial,
                       float*       __restrict__ out) {
    const int b   = blockIdx.x;
    const int t   = threadIdx.x;     // one slab-column per lane (64 slabs)

    float acc[NPART];
#pragma unroll
    for (int k = 0; k < NPART; ++k)
        acc[k] = partial[(long)k * NBLK + b * SLABS + t];

#pragma unroll
    for (int k = 0; k < NPART; ++k) {
#pragma unroll
        for (int off = 32; off > 0; off >>= 1)
            acc[k] += __shfl_down(acc[k], off);
    }

    if (t == 0) {
        float s = 0.f;
#pragma unroll
        for (int c = 0; c < C_CLS; ++c) {
            const float is = acc[c * 3 + 0];
            const float o  = acc[c * 3 + 1];
            const float cn = acc[c * 3 + 2];
            s += (2.f * o + 1.f) / (is + cn + 1.f);
        }
        out[b] = -s * (1.f / (float)C_CLS);
    }
}

extern "C" void kernel_launch(void* const* d_in, const int* in_sizes, int n_in,
                              void* d_out, int out_size, void* d_ws, size_t ws_size,
                              hipStream_t stream) {
    const float* pred = (const float*)d_in[0];
    const int*   tgt  = (const int*)d_in[1];
    float*       out  = (float*)d_out;
    float*       partial = (float*)d_ws;   // 48 * 512 * 4 B = 98304 B

    dice_partial_kernel<<<NBLK, 256, 0, stream>>>(pred, tgt, partial);
    dice_final_kernel<<<BATCH, 64, 0, stream>>>(partial, out);
}

// Round 7
// 28.836 us; speedup vs baseline: 1.8740x; 1.0383x over previous
//
#include <hip/hip_runtime.h>

// SoftDiceLoss: predictions [B=8, C=16, H=512, W=512] fp32, targets [B,H,W] int32.
// out[b] = -(1/C) * sum_c (2*overlap[b,c] + 1) / (i_sum[b,c] + count[b,c] + 1)
//
// Stage 1: 512 blocks = (8 batches x 64 slabs of 4096 positions) x 256 thr.
//   Each thread owns 16 positions; targets packed 4 bits each into ONE u64
//   (tpack). The 16 pred class-segments stream SEQUENTIALLY (contiguous
//   16 KB stream, 4 float4 in flight/thread). Per class: 5-VALU exact
//   nibble==c mask on tpack; count = popcount. Wave reduction uses DPP
//   row_shr/row_bcast (pure VALU, zero DS ops; rocPRIM pattern) -> wave
//   sum in lane 63 -> LDS -> partial[comp][block] in d_ws.
// Stage 2: 8 blocks x 64 threads: thread t reduces one slab-column,
//   lane 0 computes the 16 fracs and writes out[b].

constexpr int  C_CLS   = 16;
constexpr long HW      = 512L * 512L;   // 262144 positions per (b,c) plane
constexpr int  BATCH   = 8;
constexpr int  SLAB    = 4096;          // positions per block
constexpr int  SLABS   = (int)(HW / SLAB);   // 64 per batch
constexpr int  NBLK    = BATCH * SLABS;      // 512
constexpr int  NPART   = 3 * C_CLS;          // 48 components

// Full wave64 sum via DPP (rocPRIM pattern). Result valid in lane 63.
__device__ __forceinline__ float wave_reduce_dpp(float x) {
    int t;
    t = __builtin_amdgcn_update_dpp(0, __float_as_int(x), 0x111, 0xf, 0xf, true); // row_shr:1
    x += __int_as_float(t);
    t = __builtin_amdgcn_update_dpp(0, __float_as_int(x), 0x112, 0xf, 0xf, true); // row_shr:2
    x += __int_as_float(t);
    t = __builtin_amdgcn_update_dpp(0, __float_as_int(x), 0x114, 0xf, 0xf, true); // row_shr:4
    x += __int_as_float(t);
    t = __builtin_amdgcn_update_dpp(0, __float_as_int(x), 0x118, 0xf, 0xf, true); // row_shr:8
    x += __int_as_float(t);
    t = __builtin_amdgcn_update_dpp(0, __float_as_int(x), 0x142, 0xa, 0xf, true); // row_bcast:15
    x += __int_as_float(t);
    t = __builtin_amdgcn_update_dpp(0, __float_as_int(x), 0x143, 0xc, 0xf, true); // row_bcast:31
    x += __int_as_float(t);
    return x;
}

__global__ __launch_bounds__(256, 8)
void dice_partial_kernel(const float* __restrict__ pred,
                         const int*   __restrict__ tgt,
                         float*       __restrict__ partial) {
    const int g    = blockIdx.x;
    const int slab = g & (SLABS - 1);
    const int b    = g >> 6;
    const int tid  = threadIdx.x;
    const int lane = tid & 63;
    const int wv   = tid >> 6;

    const long sbase = (long)slab * SLAB;        // within plane
    const int* tb = tgt + (long)b * HW + sbase;

    // pack this thread's 16 target values into one u64 (4 bits each)
    unsigned long long tpack = 0ull;
#pragma unroll
    for (int j = 0; j < 4; ++j) {
        const int4 tv = *reinterpret_cast<const int4*>(tb + j * 1024 + tid * 4);
        const unsigned nib = (unsigned)tv.x | ((unsigned)tv.y << 4)
                           | ((unsigned)tv.z << 8) | ((unsigned)tv.w << 12);
        tpack |= (unsigned long long)nib << (16 * j);
    }

    const float* pb = pred + (long)b * C_CLS * HW + sbase;

    __shared__ float sm[4][NPART];

#pragma unroll
    for (int c = 0; c < C_CLS; ++c) {
        // exact per-nibble (t==c) mask: bit 4i of m = match at position i
        unsigned long long x = tpack ^ ((unsigned long long)c * 0x1111111111111111ull);
        x |= x >> 2;
        x |= x >> 1;
        const unsigned long long m = ~x & 0x1111111111111111ull;

        float isum = 0.f, ov = 0.f;
#pragma unroll
        for (int j = 0; j < 4; ++j) {
            const float4 p = *reinterpret_cast<const float4*>(
                pb + (long)c * HW + j * 1024 + tid * 4);
            const unsigned mb = (unsigned)(m >> (16 * j));
            isum += (p.x + p.y) + (p.z + p.w);
            ov   += ((mb & 0x0001u) ? p.x : 0.f) + ((mb & 0x0010u) ? p.y : 0.f)
                  + ((mb & 0x0100u) ? p.z : 0.f) + ((mb & 0x1000u) ? p.w : 0.f);
        }
        float cntf = (float)__popcll(m);

        isum = wave_reduce_dpp(isum);
        ov   = wave_reduce_dpp(ov);
        cntf = wave_reduce_dpp(cntf);
        if (lane == 63) {
            sm[wv][c * 3 + 0] = isum;
            sm[wv][c * 3 + 1] = ov;
            sm[wv][c * 3 + 2] = cntf;
        }
    }

    __syncthreads();
    if (tid < NPART) {
        // component-major layout: partial[comp][block] for coalesced stage-2
        partial[(long)tid * NBLK + g] =
            (sm[0][tid] + sm[1][tid]) + (sm[2][tid] + sm[3][tid]);
    }
}

__global__ __launch_bounds__(64)
void dice_final_kernel(const float* __restrict__ partial,
                       float*       __restrict__ out) {
    const int b = blockIdx.x;
    const int t = threadIdx.x;     // one slab-column per lane (64 slabs)

    float acc[NPART];
#pragma unroll
    for (int k = 0; k < NPART; ++k)
        acc[k] = partial[(long)k * NBLK + b * SLABS + t];

#pragma unroll
    for (int k = 0; k < NPART; ++k)
        acc[k] = wave_reduce_dpp(acc[k]);   // totals valid in lane 63

    if (t == 63) {
        float s = 0.f;
#pragma unroll
        for (int c = 0; c < C_CLS; ++c) {
            const float is = acc[c * 3 + 0];
            const float o  = acc[c * 3 + 1];
            const float cn = acc[c * 3 + 2];
            s += (2.f * o + 1.f) / (is + cn + 1.f);
        }
        out[b] = -s * (1.f / (float)C_CLS);
    }
}

extern "C" void kernel_launch(void* const* d_in, const int* in_sizes, int n_in,
                              void* d_out, int out_size, void* d_ws, size_t ws_size,
                              hipStream_t stream) {
    const float* pred = (const float*)d_in[0];
    const int*   tgt  = (const int*)d_in[1];
    float*       out  = (float*)d_out;
    float*       partial = (float*)d_ws;   // 48 * 512 * 4 B = 98304 B

    dice_partial_kernel<<<NBLK, 256, 0, stream>>>(pred, tgt, partial);
    dice_final_kernel<<<BATCH, 64, 0, stream>>>(partial, out);
}